// Round 6
// baseline (463.333 us; speedup 1.0000x reference)
//
#include <hip/hip_runtime.h>

#define BATCH 8192
#define DIM   2048   // IN_DIM == OUT_DIM
#define DEPTH 5
#define KDIM  2048

// Fragment-ready operand layout: operand (M x K) stored as chunks of 8 bf16.
// chunk(tile, kt, l) = X[m = tile*16 + (l&15)][k = kt*32 + (l>>4)*8 .. +8]
// flat index = ((tile*64 + kt)*64 + l) * 8 ushorts.  A lane's MFMA fragment
// load is then base + lane*16 B : perfectly coalesced global_load_dwordx4,
// no LDS round-trip, no barriers in the GEMM K-loop.
#define TILE_STRIDE 32768  // 64 kt * 64 l * 8 ushorts

typedef short bf16x8_t __attribute__((ext_vector_type(8)));
typedef float f32x4_t  __attribute__((ext_vector_type(4)));

// ---- bf16 split helpers (RNE, bit-manip) ----
__device__ __forceinline__ unsigned short f2bf(float f) {
  unsigned u = __float_as_uint(f);
  u += 0x7fffu + ((u >> 16) & 1u);
  return (unsigned short)(u >> 16);
}
__device__ __forceinline__ float bf2f(unsigned short h) {
  return __uint_as_float(((unsigned)h) << 16);
}

// ============================================================================
// Fused prep (one dispatch):
//  blocks [0, 8192)      : split x -> frag-ready xhi/xlo chunks
//  blocks [8192, 12288)  : W (KxN) -> transpose+split -> frag-ready whi/wlo
//  blocks [12288, 12296) : bias2[j] = b[j] + (1/2048)*prod_d cos(hdw[d,j,0])^2
//    (scan preserves uniformity along axis1 -> rolls cancel; phases vanish)
// ============================================================================
__global__ void prep_fused_kernel(const float* __restrict__ x,
                                  const float* __restrict__ hdw,
                                  const float* __restrict__ W,
                                  const float* __restrict__ bias,
                                  float* __restrict__ bias2,
                                  unsigned short* __restrict__ xhi,
                                  unsigned short* __restrict__ xlo,
                                  unsigned short* __restrict__ whi,
                                  unsigned short* __restrict__ wlo) {
  __shared__ float tile[32][33];
  const int b = blockIdx.x;
  const int tid = threadIdx.x;

  if (b < 8192) {  // ---- split x into frag-ready chunks ----
    size_t g = (size_t)b * 256 + tid;       // chunk id, 0..2097151
    const int l = (int)(g & 63);
    const size_t grp = g >> 6;              // tile*64 + kt
    const size_t m = (grp >> 6) * 16 + (l & 15);
    const size_t k = (grp & 63) * 32 + (size_t)(l >> 4) * 8;
    const float4* xp = (const float4*)(x + m * KDIM + k);
    float4 v0 = xp[0], v1 = xp[1];
    float v[8] = {v0.x, v0.y, v0.z, v0.w, v1.x, v1.y, v1.z, v1.w};
    bf16x8_t h, lo;
#pragma unroll
    for (int j = 0; j < 8; ++j) {
      unsigned short hj = f2bf(v[j]);
      h[j] = (short)hj;
      lo[j] = (short)f2bf(v[j] - bf2f(hj));
    }
    ((bf16x8_t*)xhi)[g] = h;
    ((bf16x8_t*)xlo)[g] = lo;
  } else if (b < 12288) {  // ---- transpose+split W into frag-ready chunks ----
    const int t = b - 8192;
    const int tx = tid & 31;   // 0..31
    const int ty = tid >> 5;   // 0..7
    const int n0 = (t & 63) * 32;
    const int k0 = (t >> 6) * 32;
#pragma unroll
    for (int r = 0; r < 32; r += 8)
      tile[ty + r][tx] = W[(size_t)(k0 + ty + r) * DIM + n0 + tx];
    __syncthreads();
    // 128 chunks (2 n-subtiles x 64 lanes); threads 0-127 write hi, 128-255 lo
    const int c = tid & 127, half = tid >> 7;
    const int sub = c >> 6, l = c & 63;
    const int nn = sub * 16 + (l & 15);
    const int kc = l >> 4;
    bf16x8_t outv;
#pragma unroll
    for (int j = 0; j < 8; ++j) {
      float vv = tile[kc * 8 + j][nn];       // = W[k0+kc*8+j][n0+nn]
      unsigned short hj = f2bf(vv);
      outv[j] = half ? (short)f2bf(vv - bf2f(hj)) : (short)hj;
    }
    const size_t tile_n = (size_t)(t & 63) * 2 + sub;
    const size_t o = (tile_n * 64 + (t >> 6)) * 64 + l;  // chunk id
    ((bf16x8_t*)(half ? wlo : whi))[o] = outv;
  } else {  // ---- bias2 ----
    int j = (b - 12288) * 256 + tid;
    float p = 1.0f;
#pragma unroll
    for (int d = 0; d < DEPTH; ++d)
      p *= cosf(hdw[(size_t)d * DIM * DIM + (size_t)j * DIM]);
    bias2[j] = bias[j] + p * p * (1.0f / 2048.0f);
  }
}

// ============================================================================
// Barrier-free GEMM: C = A@W via bf16x3 MFMA; out = tanh(C + bias2).
// 128x128 block tile, 4 waves (2x2), wave = 64x64 = 4x4 of 16x16x32 MFMA.
// Frag-ready operands loaded straight from global (L1/L2), register dbuf,
// no LDS / no barriers -> compiler emits partial-vmcnt pipelining.
// launch_bounds(256,3): 3 waves/EU = 3 blocks/CU (152 regs used <= 512/3).
// XCD swizzle: 8 consecutive blocks on one XCD share bn (B strip L2-hot).
// NOTE: last iteration prefetches one kt past the strip; ws layout places
// bias2 after wTlo so these reads stay inside the workspace.
// ============================================================================
__global__ __launch_bounds__(256, 3) void gemm_direct_kernel(
    const unsigned short* __restrict__ Ah, const unsigned short* __restrict__ Al,
    const unsigned short* __restrict__ Bh, const unsigned short* __restrict__ Bl,
    const float* __restrict__ bias2, float* __restrict__ out) {
  const int tid  = threadIdx.x;
  const int wave = tid >> 6;
  const int lane = tid & 63;

  // XCD-aware remap: id%8 ~ XCD. Per XCD, 8 consecutive q share bn.
  const int id = blockIdx.y * 64 + blockIdx.x;
  const int xcd = id & 7, q = id >> 3;
  const int bn = q >> 3;                 // 0..15
  const int bm = (q & 7) * 8 + xcd;      // 0..63

  const int wm = wave >> 1, wn = wave & 1;
  const int l15 = lane & 15, kl = lane >> 4;

  const int tm0 = bm * 8 + wm * 4;  // m-tile (16 rows) base
  const int tn0 = bn * 8 + wn * 4;

  const unsigned short* pAh[4]; const unsigned short* pAl[4];
  const unsigned short* pBh[4]; const unsigned short* pBl[4];
#pragma unroll
  for (int i = 0; i < 4; ++i) {
    pAh[i] = Ah + (size_t)(tm0 + i) * TILE_STRIDE;
    pAl[i] = Al + (size_t)(tm0 + i) * TILE_STRIDE;
    pBh[i] = Bh + (size_t)(tn0 + i) * TILE_STRIDE;
    pBl[i] = Bl + (size_t)(tn0 + i) * TILE_STRIDE;
  }
  int voff = lane * 8;  // ushort offset within strip; +512 per kt

  const f32x4_t vzero = {0.f, 0.f, 0.f, 0.f};
  f32x4_t acc[4][4];
#pragma unroll
  for (int i = 0; i < 4; ++i)
#pragma unroll
    for (int j = 0; j < 4; ++j) acc[i][j] = vzero;

  bf16x8_t ah[4], al[4], bh[4], bl[4];
#pragma unroll
  for (int i = 0; i < 4; ++i) {
    ah[i] = *(const bf16x8_t*)(pAh[i] + voff);
    al[i] = *(const bf16x8_t*)(pAl[i] + voff);
    bh[i] = *(const bf16x8_t*)(pBh[i] + voff);
    bl[i] = *(const bf16x8_t*)(pBl[i] + voff);
  }

#pragma unroll 2
  for (int kt = 0; kt < KDIM / 32; ++kt) {
    // prefetch kt+1 (register double-buffer; OOB-safe, see note above)
    const int nv = voff + 512;
    bf16x8_t nah[4], nal[4], nbh[4], nbl[4];
#pragma unroll
    for (int i = 0; i < 4; ++i) {
      nah[i] = *(const bf16x8_t*)(pAh[i] + nv);
      nal[i] = *(const bf16x8_t*)(pAl[i] + nv);
      nbh[i] = *(const bf16x8_t*)(pBh[i] + nv);
      nbl[i] = *(const bf16x8_t*)(pBl[i] + nv);
    }
#pragma unroll
    for (int i = 0; i < 4; ++i)
#pragma unroll
      for (int j = 0; j < 4; ++j) {
        acc[i][j] = __builtin_amdgcn_mfma_f32_16x16x32_bf16(ah[i], bh[j], acc[i][j], 0, 0, 0);
        acc[i][j] = __builtin_amdgcn_mfma_f32_16x16x32_bf16(ah[i], bl[j], acc[i][j], 0, 0, 0);
        acc[i][j] = __builtin_amdgcn_mfma_f32_16x16x32_bf16(al[i], bh[j], acc[i][j], 0, 0, 0);
      }
#pragma unroll
    for (int i = 0; i < 4; ++i) {
      ah[i] = nah[i]; al[i] = nal[i]; bh[i] = nbh[i]; bl[i] = nbl[i];
    }
    voff = nv;
  }

  // Epilogue: C/D layout col = lane&15, row = (lane>>4)*4 + reg  [m89/m91]
  const int orow0 = bm * 128 + wm * 64;
  const int ocol0 = bn * 128 + wn * 64;
#pragma unroll
  for (int j = 0; j < 4; ++j) {
    const int col = ocol0 + j * 16 + l15;
    const float b2 = bias2[col];
#pragma unroll
    for (int i = 0; i < 4; ++i) {
      const int row = orow0 + i * 16 + kl * 4;
#pragma unroll
      for (int r = 0; r < 4; ++r) {
        float z = acc[i][j][r] + b2;
        // tanh(z) = 1 - 2/(exp(2z)+1)
        float e = __expf(2.0f * z);
        out[(size_t)(row + r) * DIM + col] = 1.0f - 2.0f / (e + 1.0f);
      }
    }
  }
}

// ============================================================================
extern "C" void kernel_launch(void* const* d_in, const int* in_sizes, int n_in,
                              void* d_out, int out_size, void* d_ws, size_t ws_size,
                              hipStream_t stream) {
  const float* x   = (const float*)d_in[0];
  const float* hdw = (const float*)d_in[1];
  const float* W   = (const float*)d_in[2];
  const float* b   = (const float*)d_in[3];
  float* out = (float*)d_out;

  // workspace layout (~80.01 MB); bias2 LAST so tail prefetch stays in ws
  char* ws = (char*)d_ws;
  unsigned short* xhi  = (unsigned short*)ws;                       // 32 MB
  unsigned short* xlo  = xhi + (size_t)BATCH * DIM;                 // 32 MB
  unsigned short* wThi = xlo + (size_t)BATCH * DIM;                 // 8 MB
  unsigned short* wTlo = wThi + (size_t)DIM * DIM;                  // 8 MB
  float*          bias2 = (float*)(wTlo + (size_t)DIM * DIM);       // 8 KB

  prep_fused_kernel<<<12296, 256, 0, stream>>>(
      x, hdw, W, b, bias2, xhi, xlo, wThi, wTlo);
  gemm_direct_kernel<<<dim3(BATCH / 128, DIM / 128), 256, 0, stream>>>(
      xhi, xlo, wThi, wTlo, bias2, out);
}